// Round 4
// baseline (884.880 us; speedup 1.0000x reference)
//
#include <hip/hip_runtime.h>
#include <stdint.h>

// Problem constants
#define N_ROWS 8192
#define D_DIM  1024
#define M_CENT 20000
#define M_PAD  20224          // 79 * 256
#define M_TILES 79            // 256-wide center tiles
#define Y_DIM  256
#define BM 64                 // rows of X per block
#define BN 256                // centers per M-iteration (wave tile 64x64)
#define BK2 32                // K-chunk of D (double-buffered)
#define NKC (D_DIM / BK2)     // 32 k-chunks
#define MSPLIT 8
#define TILES_PER_SPLIT 10    // ceil(79/8)
#define LDSP_STRIDE 264       // 256 + 8 pad: 33 16B-slots/row == 1 mod 8 -> conflict-free

typedef __attribute__((ext_vector_type(4))) float  f32x4;
typedef __attribute__((ext_vector_type(8))) __bf16 bf16x8;

__device__ __forceinline__ unsigned short f2bf(float f) {
    union { float f; unsigned u; } v; v.f = f;
    unsigned u = v.u;
    u += 0x7FFFu + ((u >> 16) & 1u);   // RNE
    return (unsigned short)(u >> 16);
}

// async global->LDS, 16B per lane. LDS dest must be wave-uniform base + lane*16.
__device__ __forceinline__ void gll16(void* lds, const void* g) {
    __builtin_amdgcn_global_load_lds(
        (const __attribute__((address_space(1))) void*)g,
        (__attribute__((address_space(3))) void*)lds, 16, 0, 0);
}

// cast fp32 rows -> bf16, compute fp32 row sum-of-squares; pad rows -> zeros
__global__ void cast_rows_kernel(const float* __restrict__ src,
                                 unsigned short* __restrict__ dst,
                                 float* __restrict__ sq, int nrows_valid) {
    int row = blockIdx.x;
    int t = threadIdx.x;  // 256 threads, 4 floats each = 1024 = D_DIM
    float s = 0.f;
    if (row < nrows_valid) {
        float4 v = ((const float4*)(src + (size_t)row * D_DIM))[t];
        s = v.x * v.x + v.y * v.y + v.z * v.z + v.w * v.w;
        ushort4 o;
        o.x = f2bf(v.x); o.y = f2bf(v.y); o.z = f2bf(v.z); o.w = f2bf(v.w);
        ((ushort4*)(dst + (size_t)row * D_DIM))[t] = o;
    } else {
        ((ushort4*)(dst + (size_t)row * D_DIM))[t] = make_ushort4(0, 0, 0, 0);
    }
    __shared__ float red[4];
    for (int off = 32; off; off >>= 1) s += __shfl_down(s, off, 64);
    if ((t & 63) == 0) red[t >> 6] = s;
    __syncthreads();
    if (t == 0) sq[row] = red[0] + red[1] + red[2] + red[3];
}

// W [M][Y] fp32 -> WT [Y][M_PAD] bf16, pad rows (centers >= M_CENT) -> 0
__global__ void cast_wT_kernel(const float* __restrict__ w,
                               unsigned short* __restrict__ wT) {
    __shared__ float tile[32][33];
    int k0 = blockIdx.x * 32;   // center dim
    int y0 = blockIdx.y * 32;   // Y dim
    int tx = threadIdx.x & 31;
    int ty = threadIdx.x >> 5;  // 0..7
    #pragma unroll
    for (int i = 0; i < 4; ++i) {
        int k = k0 + ty + i * 8;
        float v = (k < M_CENT) ? w[(size_t)k * Y_DIM + y0 + tx] : 0.f;
        tile[tx][ty + i * 8] = v;     // tile[y_local][k_local]
    }
    __syncthreads();
    #pragma unroll
    for (int i = 0; i < 4; ++i) {
        int yl = ty + i * 8;
        wT[(size_t)(y0 + yl) * M_PAD + k0 + tx] = f2bf(tile[yl][tx]);
    }
}

// Fused flash-style kernel, wave tile 64x64, BK=32 double-buffered staging.
// Pipeline per kc: barrier -> issue async stage(kc+1) into other buf -> MFMA(kc).
// The vmcnt(0) drain at the NEXT barrier waits on loads that had a full MFMA
// phase to land (R3 lesson: stage->drain->MFMA had zero intra-wave overlap).
// BK=32 rows are 64B = 4 x 16B chunks: 64 lanes (16 rows x 4 quads) tile the
// 32 banks exactly -> frag ds_read_b128 conflict-free with NO swizzle.
// lds.p aliases the staging buffers (live ranges disjoint across barriers).
// launch_bounds(256,2): ~190 unified regs/wave must not spill (R2 lesson).
__global__ void __launch_bounds__(256, 2)
fused_kernel(const unsigned short* __restrict__ Xb,
             const unsigned short* __restrict__ Zb,
             const unsigned short* __restrict__ WbT,
             const float* __restrict__ xsq,
             const float* __restrict__ zsq,
             const int* __restrict__ bwp,
             float* __restrict__ out) {
    __shared__ union {
        struct {
            unsigned short x[2][BM * BK2];   // 2 x 4 KB
            unsigned short z[2][BN * BK2];   // 2 x 16 KB
        } s1;                                // 40 KB
        unsigned short p[BM * LDSP_STRIDE];  // 33.8 KB
    } lds;
    __shared__ float lds_xsq[BM];
    __shared__ float lds_zsq[BN];

    const int t    = threadIdx.x;
    const int wave = t >> 6;
    const int lane = t & 63;
    const int quad = lane >> 4;
    const int l16  = lane & 15;

    const int row0 = blockIdx.x * BM;
    int mt = blockIdx.y * TILES_PER_SPLIT;
    int mt_end = mt + TILES_PER_SPLIT;
    if (mt_end > M_TILES) mt_end = M_TILES;

    // bandwidth: int32 per harness convention (Python int 10); tolerate float bits too
    int bwi = *bwp;
    float bw;
    if (bwi > 0 && bwi < 1000000) bw = (float)bwi;
    else { union { int i; float f; } u; u.i = bwi; bw = u.f; }
    const float inv_bw = 1.0f / bw;

    if (t < BM) lds_xsq[t] = xsq[row0 + t];

    // per-thread staging source offsets (row-major, natural chunk order)
    const int xrow = t >> 2, xch = t & 3;
    const unsigned short* xsrc = Xb + (size_t)(row0 + xrow) * D_DIM + xch * 8;
    size_t zoff[4];
    #pragma unroll
    for (int i = 0; i < 4; ++i) {
        int lin = t + i * 256;
        zoff[i] = (size_t)(lin >> 2) * D_DIM + (lin & 3) * 8;
    }

    const f32x4 vzero = {0.f, 0.f, 0.f, 0.f};
    f32x4 Oacc[16];
    #pragma unroll
    for (int i = 0; i < 16; ++i) Oacc[i] = vzero;

    for (; mt < mt_end; ++mt) {
        // protect prev iteration's lds.p reads (Phase 3) from staging overwrite
        __syncthreads();

        const int m0 = mt * BN;
        const unsigned short* zsrc = Zb + (size_t)m0 * D_DIM;
        lds_zsq[t] = zsq[m0 + t];   // BN == blockDim.x == 256

        f32x4 S[16];
        #pragma unroll
        for (int i = 0; i < 16; ++i) S[i] = vzero;

        // prologue: stage kc=0 into buf 0
        gll16(&lds.s1.x[0][t * 8], xsrc);
        #pragma unroll
        for (int i = 0; i < 4; ++i)
            gll16(&lds.s1.z[0][(t + i * 256) * 8], zsrc + zoff[i]);

        // -------- Phase 1: S[64x256] = X * Z^T, pipelined over 32 k-chunks ----
        #pragma unroll 1
        for (int kc2 = 0; kc2 < NKC / 2; ++kc2) {
            #pragma unroll
            for (int half = 0; half < 2; ++half) {
                const int kc = kc2 * 2 + half;       // buffer = kc & 1 = half
                __syncthreads();                      // drains buf[half] loads
                if (kc < NKC - 1) {                   // stage kc+1 -> other buf
                    const int nb = half ^ 1;
                    const size_t kb = (size_t)(kc + 1) * BK2;
                    gll16(&lds.s1.x[nb][t * 8], xsrc + kb);
                    #pragma unroll
                    for (int i = 0; i < 4; ++i)
                        gll16(&lds.s1.z[nb][(t + i * 256) * 8], zsrc + zoff[i] + kb);
                }
                bf16x8 a[4], b[4];
                #pragma unroll
                for (int it = 0; it < 4; ++it)
                    a[it] = *(const bf16x8*)&lds.s1.x[half][(it * 16 + l16) * BK2 + quad * 8];
                #pragma unroll
                for (int jt = 0; jt < 4; ++jt)
                    b[jt] = *(const bf16x8*)&lds.s1.z[half][(wave * 64 + jt * 16 + l16) * BK2 + quad * 8];
                #pragma unroll
                for (int it = 0; it < 4; ++it)
                    #pragma unroll
                    for (int jt = 0; jt < 4; ++jt)
                        S[it * 4 + jt] = __builtin_amdgcn_mfma_f32_16x16x32_bf16(
                            a[it], b[jt], S[it * 4 + jt], 0, 0, 0);
            }
        }
        __syncthreads();   // all frag reads of last buf done before p overwrites

        // -------- Phase 2: P = exp(-sqrt(d2)/bw) -> lds.p (bf16) --------
        #pragma unroll
        for (int it = 0; it < 4; ++it) {
            #pragma unroll
            for (int jt = 0; jt < 4; ++jt) {
                f32x4 s4 = S[it * 4 + jt];
                const int col = wave * 64 + jt * 16 + l16;
                const float zq = lds_zsq[col];
                #pragma unroll
                for (int r = 0; r < 4; ++r) {
                    const int row = it * 16 + quad * 4 + r;   // C-layout: row=(lane>>4)*4+reg
                    float d2 = lds_xsq[row] + zq - 2.0f * s4[r];
                    d2 = fmaxf(d2, 0.f);
                    float p = __expf(-sqrtf(d2) * inv_bw);
                    lds.p[row * LDSP_STRIDE + col] = f2bf(p);
                }
            }
        }
        __syncthreads();

        // -------- Phase 3: O += P[64x256] * Wtile[256x256] --------
        #pragma unroll
        for (int ks = 0; ks < 8; ++ks) {
            const int koff = ks * 32 + quad * 8;
            bf16x8 a[4], b[4];
            #pragma unroll
            for (int rt = 0; rt < 4; ++rt)
                a[rt] = *(const bf16x8*)&lds.p[(rt * 16 + l16) * LDSP_STRIDE + koff];
            #pragma unroll
            for (int ct = 0; ct < 4; ++ct) {
                const int y = wave * 64 + ct * 16 + l16;
                b[ct] = *(const bf16x8*)(WbT + (size_t)y * M_PAD + m0 + koff);
            }
            #pragma unroll
            for (int rt = 0; rt < 4; ++rt)
                #pragma unroll
                for (int ct = 0; ct < 4; ++ct)
                    Oacc[rt * 4 + ct] = __builtin_amdgcn_mfma_f32_16x16x32_bf16(
                        a[rt], b[ct], Oacc[rt * 4 + ct], 0, 0, 0);
        }
    }

    // -------- epilogue: accumulate M-splits via device-scope fp32 atomics --------
    #pragma unroll
    for (int rt = 0; rt < 4; ++rt) {
        #pragma unroll
        for (int ct = 0; ct < 4; ++ct) {
            f32x4 v = Oacc[rt * 4 + ct];
            const int y = wave * 64 + ct * 16 + l16;
            #pragma unroll
            for (int r = 0; r < 4; ++r) {
                const int row = row0 + rt * 16 + quad * 4 + r;
                atomicAdd(&out[(size_t)row * Y_DIM + y], v[r]);
            }
        }
    }
}

extern "C" void kernel_launch(void* const* d_in, const int* in_sizes, int n_in,
                              void* d_out, int out_size, void* d_ws, size_t ws_size,
                              hipStream_t stream) {
    const float* X = (const float*)d_in[0];
    const float* Z = (const float*)d_in[1];
    const float* W = (const float*)d_in[2];
    const int*  bw = (const int*)d_in[3];
    float* out = (float*)d_out;

    char* ws = (char*)d_ws;
    size_t off = 0;
    unsigned short* Xb  = (unsigned short*)(ws + off); off += (size_t)N_ROWS * D_DIM * 2;
    unsigned short* Zb  = (unsigned short*)(ws + off); off += (size_t)M_PAD * D_DIM * 2;
    unsigned short* WbT = (unsigned short*)(ws + off); off += (size_t)Y_DIM * M_PAD * 2;
    float* xsq = (float*)(ws + off); off += (size_t)N_ROWS * 4;
    float* zsq = (float*)(ws + off); off += (size_t)M_PAD * 4;
    // total ws use: ~68.7 MB

    hipMemsetAsync(d_out, 0, (size_t)out_size * sizeof(float), stream);
    cast_rows_kernel<<<N_ROWS, 256, 0, stream>>>(X, Xb, xsq, N_ROWS);
    cast_rows_kernel<<<M_PAD, 256, 0, stream>>>(Z, Zb, zsq, M_CENT);
    cast_wT_kernel<<<dim3(M_PAD / 32, Y_DIM / 32), 256, 0, stream>>>(W, WbT);
    fused_kernel<<<dim3(N_ROWS / BM, MSPLIT), 256, 0, stream>>>(Xb, Zb, WbT, xsq, zsq, bw, out);
}

// Round 5
// 809.570 us; speedup vs baseline: 1.0930x; 1.0930x over previous
//
#include <hip/hip_runtime.h>
#include <stdint.h>

// Problem constants
#define N_ROWS 8192
#define D_DIM  1024
#define M_CENT 20000
#define M_PAD  20224          // 79 * 256
#define M_TILES 79            // 256-wide center tiles
#define Y_DIM  256
#define BM 64                 // rows of X per block
#define BN 256                // centers per M-iteration (wave tile 64x64)
#define MSPLIT 8
#define TILES_PER_SPLIT 10    // ceil(79/8)
#define LDSP_STRIDE 264       // 256+8 pad: P-frag ds_read_b128 conflict-free
#define NKT 32                // K=1024 / 32 per MFMA step
#define PANEL_X (NKT * 512)   // 16 rows x 1024 k, frag-packed = 16384 elements
#define NKT_M 632             // M_PAD / 32
#define PANEL_W (NKT_M * 512) // 16 y-cols x M_PAD, frag-packed

// Fragment-linear packing: element (row,k) of a 16-row panel lives at
//   panel*PANEL + (k>>5)*512 + ((k>>3)&3)*128 + (row&15)*8 + (k&7)
// so a wave's MFMA fragment (lane = quad*16+l16 reads [row=l16][k=quad*8+j])
// is one contiguous, coalesced 1 KB global_load_dwordx4 block.

typedef __attribute__((ext_vector_type(4))) float  f32x4;
typedef __attribute__((ext_vector_type(8))) __bf16 bf16x8;

__device__ __forceinline__ unsigned short f2bf(float f) {
    union { float f; unsigned u; } v; v.f = f;
    unsigned u = v.u;
    u += 0x7FFFu + ((u >> 16) & 1u);   // RNE
    return (unsigned short)(u >> 16);
}

// fp32 rows -> bf16 frag-packed panels + fp32 row sum-of-squares; pad rows -> 0
__global__ void pack_rows_kernel(const float* __restrict__ src,
                                 unsigned short* __restrict__ dst,
                                 float* __restrict__ sq, int nrows_valid) {
    int row = blockIdx.x;
    int t = threadIdx.x;  // 256 threads, 4 consecutive floats each (k = 4t..4t+3)
    int p = row >> 4, m = row & 15;
    float s = 0.f;
    ushort4 o = make_ushort4(0, 0, 0, 0);
    if (row < nrows_valid) {
        float4 v = ((const float4*)(src + (size_t)row * D_DIM))[t];
        s = v.x * v.x + v.y * v.y + v.z * v.z + v.w * v.w;
        o.x = f2bf(v.x); o.y = f2bf(v.y); o.z = f2bf(v.z); o.w = f2bf(v.w);
    }
    // kt = t>>3, quad = (t>>1)&3, j0 = (t&1)*4
    size_t obase = (size_t)p * PANEL_X + (size_t)(t >> 3) * 512
                 + (size_t)((t >> 1) & 3) * 128 + m * 8 + (t & 1) * 4;
    *(ushort4*)(dst + obase) = o;
    __shared__ float red[4];
    for (int off = 32; off; off >>= 1) s += __shfl_down(s, off, 64);
    if ((t & 63) == 0) red[t >> 6] = s;
    __syncthreads();
    if (t == 0) sq[row] = red[0] + red[1] + red[2] + red[3];
}

// W [M][Y] fp32 -> frag-packed WTp: panel p = y>>4 over M; pad m>=M_CENT -> 0
__global__ void pack_wT_kernel(const float* __restrict__ w,
                               unsigned short* __restrict__ wTp) {
    __shared__ float tile[32][33];
    int m0 = blockIdx.x * 32;   // center dim (M_PAD/32 = 632 blocks)
    int y0 = blockIdx.y * 32;   // Y dim
    int tx = threadIdx.x & 31;
    int ty = threadIdx.x >> 5;  // 0..7
    #pragma unroll
    for (int i = 0; i < 4; ++i) {
        int mm = m0 + ty + i * 8;
        float v = (mm < M_CENT) ? w[(size_t)mm * Y_DIM + y0 + tx] : 0.f;
        tile[tx][ty + i * 8] = v;     // tile[y_local][m_local]
    }
    __syncthreads();
    #pragma unroll
    for (int i = 0; i < 4; ++i) {
        int yl = ty + i * 8;
        int p = (y0 >> 4) + (yl >> 4);
        size_t off = (size_t)p * PANEL_W + (size_t)(m0 >> 5) * 512
                   + (size_t)(tx >> 3) * 128 + (yl & 15) * 8 + (tx & 7);
        wTp[off] = f2bf(tile[yl][tx]);
    }
}

// Fused flash-style kernel. Phase 1 is BARRIER-FREE: A/B fragments load
// straight from frag-packed global (coalesced 1KB/wave), even/odd register
// double-buffer -> compiler emits fine-grained vmcnt interleave (no
// __syncthreads to force vmcnt(0) drains — R4 lesson). LDS holds only the
// P round-trip for Phase 3. launch_bounds(256,2): ~230 unified regs, no spill.
__global__ void __launch_bounds__(256, 2)
fused_kernel(const unsigned short* __restrict__ Xp,
             const unsigned short* __restrict__ Zp,
             const unsigned short* __restrict__ WTp,
             const float* __restrict__ xsq,
             const float* __restrict__ zsq,
             const int* __restrict__ bwp,
             float* __restrict__ out) {
    __shared__ unsigned short lds_p[BM * LDSP_STRIDE];  // 33 KB
    __shared__ float lds_xsq[BM];

    const int t    = threadIdx.x;
    const int wave = t >> 6;
    const int lane = t & 63;
    const int quad = lane >> 4;
    const int l16  = lane & 15;
    const int lane8 = lane * 8;

    const int row0 = blockIdx.x * BM;
    int mt = blockIdx.y * TILES_PER_SPLIT;
    int mt_end = mt + TILES_PER_SPLIT;
    if (mt_end > M_TILES) mt_end = M_TILES;

    // bandwidth: int32 per harness convention (Python int 10); tolerate float bits too
    int bwi = *bwp;
    float bw;
    if (bwi > 0 && bwi < 1000000) bw = (float)bwi;
    else { union { int i; float f; } u; u.i = bwi; bw = u.f; }
    const float inv_bw = 1.0f / bw;

    if (t < BM) lds_xsq[t] = xsq[row0 + t];   // visible after first barrier

    // A panels: all 4 waves read the same X data (L1 reuse)
    const unsigned short* xp0 = Xp + (size_t)(row0 >> 4) * PANEL_X + lane8;

    const f32x4 vzero = {0.f, 0.f, 0.f, 0.f};
    f32x4 Oacc[16];
    #pragma unroll
    for (int i = 0; i < 16; ++i) Oacc[i] = vzero;

    #pragma unroll 1
    for (; mt < mt_end; ++mt) {
        const int m0 = mt * BN;
        const unsigned short* zp0 = Zp + (size_t)(mt * 16 + wave * 4) * PANEL_X + lane8;

        // per-thread zsq values for Phase 2 (issued early, latency hidden)
        float zqv[4];
        #pragma unroll
        for (int jt = 0; jt < 4; ++jt)
            zqv[jt] = zsq[m0 + wave * 64 + jt * 16 + l16];

        f32x4 S[16];
        #pragma unroll
        for (int i = 0; i < 16; ++i) S[i] = vzero;

        // -------- Phase 1: S[64x256] = X * Z^T, register-pipelined, no LDS ----
        bf16x8 ae[4], be[4], ao[4], bo[4];
        #pragma unroll
        for (int i = 0; i < 4; ++i) {
            ae[i] = *(const bf16x8*)(xp0 + (size_t)i * PANEL_X);
            be[i] = *(const bf16x8*)(zp0 + (size_t)i * PANEL_X);
        }
        #pragma unroll 1
        for (int kt2 = 0; kt2 < NKT / 2; ++kt2) {
            const unsigned short* xk = xp0 + (size_t)(2 * kt2 + 1) * 512;
            const unsigned short* zk = zp0 + (size_t)(2 * kt2 + 1) * 512;
            #pragma unroll
            for (int i = 0; i < 4; ++i) {
                ao[i] = *(const bf16x8*)(xk + (size_t)i * PANEL_X);
                bo[i] = *(const bf16x8*)(zk + (size_t)i * PANEL_X);
            }
            #pragma unroll
            for (int it = 0; it < 4; ++it)
                #pragma unroll
                for (int jt = 0; jt < 4; ++jt)
                    S[it * 4 + jt] = __builtin_amdgcn_mfma_f32_16x16x32_bf16(
                        ae[it], be[jt], S[it * 4 + jt], 0, 0, 0);
            // prefetch next even kt (last iter overruns into adjacent ws region
            // by <=1KB: loaded-but-unused, safe — DCE'd or harmless)
            #pragma unroll
            for (int i = 0; i < 4; ++i) {
                ae[i] = *(const bf16x8*)(xk + 512 + (size_t)i * PANEL_X);
                be[i] = *(const bf16x8*)(zk + 512 + (size_t)i * PANEL_X);
            }
            #pragma unroll
            for (int it = 0; it < 4; ++it)
                #pragma unroll
                for (int jt = 0; jt < 4; ++jt)
                    S[it * 4 + jt] = __builtin_amdgcn_mfma_f32_16x16x32_bf16(
                        ao[it], bo[jt], S[it * 4 + jt], 0, 0, 0);
        }

        // -------- Phase 2: P = exp(-sqrt(d2)/bw) -> lds_p (bf16) --------
        __syncthreads();   // prev mt's Phase-3 lds_p reads complete (ample slack)
        #pragma unroll
        for (int it = 0; it < 4; ++it) {
            #pragma unroll
            for (int jt = 0; jt < 4; ++jt) {
                f32x4 s4 = S[it * 4 + jt];
                const int col = wave * 64 + jt * 16 + l16;
                const float zq = zqv[jt];
                #pragma unroll
                for (int r = 0; r < 4; ++r) {
                    const int row = it * 16 + quad * 4 + r;   // C-layout: row=(lane>>4)*4+reg
                    float d2 = lds_xsq[row] + zq - 2.0f * s4[r];
                    d2 = fmaxf(d2, 0.f);
                    float p = __expf(-sqrtf(d2) * inv_bw);
                    lds_p[row * LDSP_STRIDE + col] = f2bf(p);
                }
            }
        }
        __syncthreads();

        // -------- Phase 3: O += P[64x256] * Wtile[256x256], B from packed global --
        #pragma unroll
        for (int ks = 0; ks < 8; ++ks) {
            const int koff = ks * 32 + quad * 8;
            bf16x8 a[4], b[4];
            #pragma unroll
            for (int rt = 0; rt < 4; ++rt)
                a[rt] = *(const bf16x8*)&lds_p[(rt * 16 + l16) * LDSP_STRIDE + koff];
            #pragma unroll
            for (int ct = 0; ct < 4; ++ct)
                b[ct] = *(const bf16x8*)(WTp + (size_t)(wave * 4 + ct) * PANEL_W
                                             + (size_t)(mt * 8 + ks) * 512 + lane8);
            #pragma unroll
            for (int rt = 0; rt < 4; ++rt)
                #pragma unroll
                for (int ct = 0; ct < 4; ++ct)
                    Oacc[rt * 4 + ct] = __builtin_amdgcn_mfma_f32_16x16x32_bf16(
                        a[rt], b[ct], Oacc[rt * 4 + ct], 0, 0, 0);
        }
    }

    // -------- epilogue: accumulate M-splits via device-scope fp32 atomics --------
    #pragma unroll
    for (int rt = 0; rt < 4; ++rt) {
        #pragma unroll
        for (int ct = 0; ct < 4; ++ct) {
            f32x4 v = Oacc[rt * 4 + ct];
            const int y = wave * 64 + ct * 16 + l16;
            #pragma unroll
            for (int r = 0; r < 4; ++r) {
                const int row = row0 + rt * 16 + quad * 4 + r;
                atomicAdd(&out[(size_t)row * Y_DIM + y], v[r]);
            }
        }
    }
}

extern "C" void kernel_launch(void* const* d_in, const int* in_sizes, int n_in,
                              void* d_out, int out_size, void* d_ws, size_t ws_size,
                              hipStream_t stream) {
    const float* X = (const float*)d_in[0];
    const float* Z = (const float*)d_in[1];
    const float* W = (const float*)d_in[2];
    const int*  bw = (const int*)d_in[3];
    float* out = (float*)d_out;

    char* ws = (char*)d_ws;
    size_t off = 0;
    unsigned short* Xp  = (unsigned short*)(ws + off); off += (size_t)N_ROWS * D_DIM * 2;
    unsigned short* Zp  = (unsigned short*)(ws + off); off += (size_t)M_PAD * D_DIM * 2;
    unsigned short* WTp = (unsigned short*)(ws + off); off += (size_t)Y_DIM * M_PAD * 2;
    float* xsq = (float*)(ws + off); off += (size_t)N_ROWS * 4;
    float* zsq = (float*)(ws + off); off += (size_t)M_PAD * 4;
    // total ws use: ~67.9 MB (+1KB prefetch-overrun slack stays inside ws)

    hipMemsetAsync(d_out, 0, (size_t)out_size * sizeof(float), stream);
    pack_rows_kernel<<<N_ROWS, 256, 0, stream>>>(X, Xp, xsq, N_ROWS);
    pack_rows_kernel<<<M_PAD, 256, 0, stream>>>(Z, Zp, zsq, M_CENT);
    pack_wT_kernel<<<dim3(M_PAD / 32, Y_DIM / 32), 256, 0, stream>>>(W, WTp);
    fused_kernel<<<dim3(N_ROWS / BM, MSPLIT), 256, 0, stream>>>(Xp, Zp, WTp, xsq, zsq, bw, out);
}